// Round 10
// baseline (389.645 us; speedup 1.0000x reference)
//
#include <hip/hip_runtime.h>
#include <cstdint>

constexpr int BSHIFT = 9;               // 512 nodes per bucket
constexpr int NBUCK  = 256;             // max buckets (covers 131072 nodes)
constexpr int BUCKET_CAP = 6144;        // slot capacity; E/bucket ~ Poisson(5102), 14 sigma

__device__ __forceinline__ float4 add4(float4 a, float4 b) {
    return make_float4(a.x + b.x, a.y + b.y, a.z + b.z, a.w + b.w);
}
__device__ __forceinline__ float4 mul4s(float4 a, float s) {
    return make_float4(a.x * s, a.y * s, a.z * s, a.w * s);
}

// ---------------- CSR build (bucketed, LDS-local, packed pairs) ----------------

__global__ void zero_ints(int* __restrict__ p, int n) {
    int i = blockIdx.x * blockDim.x + threadIdx.x;
    if (i < n) p[i] = 0;
}

constexpr int EPT = 16;  // edges per thread; chunk = 4096
__global__ __launch_bounds__(256) void partition_edges(
    const int* __restrict__ src, const int* __restrict__ dst,
    int* __restrict__ bucketCur, int* __restrict__ pairs, int ne) {
    __shared__ int lcnt[NBUCK];
    __shared__ int lbase[NBUCK];
    int base = blockIdx.x * (256 * EPT);
    if (threadIdx.x < NBUCK) lcnt[threadIdx.x] = 0;
    __syncthreads();
    int2 ed[EPT];
    int  rnk[EPT];
#pragma unroll
    for (int j = 0; j < EPT; ++j) {
        int e = base + j * 256 + threadIdx.x;
        if (e < ne) {
            int d = dst[e];
            ed[j] = make_int2(src[e], d);
            rnk[j] = atomicAdd(&lcnt[d >> BSHIFT], 1);
        } else {
            ed[j].y = -1;
        }
    }
    __syncthreads();
    if (threadIdx.x < NBUCK) {
        int c = lcnt[threadIdx.x];
        lbase[threadIdx.x] = c ? atomicAdd(&bucketCur[threadIdx.x], c) : 0;
    }
    __syncthreads();
#pragma unroll
    for (int j = 0; j < EPT; ++j) {
        if (ed[j].y >= 0) {
            int b = ed[j].y >> BSHIFT;
            int p = lbase[b] + rnk[j];
            if (p < BUCKET_CAP)
                pairs[(size_t)b * BUCKET_CAP + p] =
                    (ed[j].x << BSHIFT) | (ed[j].y & ((1 << BSHIFT) - 1));
        }
    }
}

__global__ void scan_buckets(const int* __restrict__ bucketCnt, int* __restrict__ bucketBase,
                             int* __restrict__ offs, int n, int ne, int nbuckets) {
    __shared__ int tmp[256];
    int c = (threadIdx.x < (unsigned)nbuckets) ? bucketCnt[threadIdx.x] : 0;
    tmp[threadIdx.x] = c;
    __syncthreads();
    for (int off = 1; off < 256; off <<= 1) {
        int t = (threadIdx.x >= (unsigned)off) ? tmp[threadIdx.x - off] : 0;
        __syncthreads();
        tmp[threadIdx.x] += t;
        __syncthreads();
    }
    if (threadIdx.x < (unsigned)nbuckets) bucketBase[threadIdx.x] = tmp[threadIdx.x] - c;
    if (threadIdx.x == 0) offs[n] = ne;
}

__global__ __launch_bounds__(256) void bucket_csr(
    const int* __restrict__ pairs, const int* __restrict__ bucketCnt,
    const int* __restrict__ bucketBase, int* __restrict__ offs,
    float* __restrict__ dinv, int* __restrict__ csr, int n) {
    constexpr int BN = 1 << BSHIFT;  // 512
    __shared__ int hist[BN];
    __shared__ int cur[BN];
    __shared__ int tmp[256];
    int b = blockIdx.x;
    int cnt  = bucketCnt[b];
    int base = bucketBase[b];
    const int* pb = pairs + (size_t)b * BUCKET_CAP;
    int nodeLo = b << BSHIFT;

    hist[threadIdx.x] = 0;
    hist[threadIdx.x + 256] = 0;
    __syncthreads();
    for (int e = threadIdx.x; e < cnt; e += 256)
        atomicAdd(&hist[pb[e] & (BN - 1)], 1);
    __syncthreads();

    int l0 = 2 * threadIdx.x, l1 = l0 + 1;
    int h0 = hist[l0], h1 = hist[l1];
    tmp[threadIdx.x] = h0 + h1;
    __syncthreads();
    for (int off = 1; off < 256; off <<= 1) {
        int t = (threadIdx.x >= (unsigned)off) ? tmp[threadIdx.x - off] : 0;
        __syncthreads();
        tmp[threadIdx.x] += t;
        __syncthreads();
    }
    int e0 = tmp[threadIdx.x] - (h0 + h1);
    int e1 = e0 + h0;
    int g0 = nodeLo + l0, g1 = nodeLo + l1;
    if (g0 < n) { offs[g0] = base + e0; dinv[g0] = rsqrtf((float)(h0 + 1)); }
    if (g1 < n) { offs[g1] = base + e1; dinv[g1] = rsqrtf((float)(h1 + 1)); }
    cur[l0] = e0;
    cur[l1] = e1;
    __syncthreads();

    for (int e = threadIdx.x; e < cnt; e += 256) {
        int p = pb[e];
        int pos = atomicAdd(&cur[p & (BN - 1)], 1);
        csr[base + pos] = ((unsigned)p) >> BSHIFT;
    }
}

// ---------------- aggregation: float4/lane, LPN lanes per node, unroll 4 (R7 proven) -----
template <int M, int S, int LPN, bool SCALE_SRC, bool RELU_BIAS>
__global__ __launch_bounds__(256) void aggregate(
    const float* __restrict__ s, const int* __restrict__ offs,
    const int* __restrict__ csr, const float* __restrict__ dinv,
    const float* __restrict__ b, float* __restrict__ out, int n) {
    int lane = threadIdx.x % LPN;
    int node = blockIdx.x * (256 / LPN) + threadIdx.x / LPN;
    if (node >= n) return;
    int f0 = lane * 4;
    bool active = f0 < M;
    float dv = dinv[node];

    float4 z = make_float4(0.f, 0.f, 0.f, 0.f);
    float4 acc0 = z, acc1 = z, acc2 = z, acc3 = z;
    if (active) {
        float4 sv = *(const float4*)&s[(size_t)node * S + f0];
        acc0 = SCALE_SRC ? mul4s(sv, dv) : sv;
    }

    int e0 = offs[node], e1 = offs[node + 1];
    int e = e0;
    for (; e + 4 <= e1; e += 4) {
        int i0 = csr[e], i1 = csr[e + 1], i2 = csr[e + 2], i3 = csr[e + 3];
        float4 v0 = z, v1 = z, v2 = z, v3 = z;
        if (active) {
            v0 = *(const float4*)&s[(size_t)i0 * S + f0];
            v1 = *(const float4*)&s[(size_t)i1 * S + f0];
            v2 = *(const float4*)&s[(size_t)i2 * S + f0];
            v3 = *(const float4*)&s[(size_t)i3 * S + f0];
        }
        if (SCALE_SRC) {
            v0 = mul4s(v0, dinv[i0]); v1 = mul4s(v1, dinv[i1]);
            v2 = mul4s(v2, dinv[i2]); v3 = mul4s(v3, dinv[i3]);
        }
        acc0 = add4(acc0, v0); acc1 = add4(acc1, v1);
        acc2 = add4(acc2, v2); acc3 = add4(acc3, v3);
    }
    for (; e < e1; ++e) {
        int sid = csr[e];
        float4 v = active ? *(const float4*)&s[(size_t)sid * S + f0] : z;
        if (SCALE_SRC) v = mul4s(v, dinv[sid]);
        acc0 = add4(acc0, v);
    }
    float4 acc = add4(add4(acc0, acc1), add4(acc2, acc3));

    if (active) {
        float4 r = mul4s(acc, dv);
        if (RELU_BIAS) {
            if (f0 + 0 < M) r.x = fmaxf(r.x + b[f0 + 0], 0.0f);
            if (f0 + 1 < M) r.y = fmaxf(r.y + b[f0 + 1], 0.0f);
            if (f0 + 2 < M) r.z = fmaxf(r.z + b[f0 + 2], 0.0f);
            if (f0 + 3 < M) r.w = fmaxf(r.w + b[f0 + 3], 0.0f);
        }
        float* o = &out[(size_t)node * S + f0];
        if (f0 + 3 < M) {
            *(float4*)o = r;
        } else {
            if (f0 + 0 < M) o[0] = r.x;
            if (f0 + 1 < M) o[1] = r.y;
            if (f0 + 2 < M) o[2] = r.z;
            if (f0 + 3 < M) o[3] = r.w;
        }
    }
}

// ---------------- fused gemm12: relu(X@W1+b1) @ W2 * dinv (NO gather inside) ----------
// Block = 32 nodes. Phase A: stage X (stride-64 rows) into LDS transposed (node-fast,
// conflict-free). Phase B: H = relu(Xs@W1+b1) -> Hs. Phase C: out = (Hs@W2)*dinv.
// W1/W2 read from global (L1/L2-resident broadcast).
__global__ __launch_bounds__(256) void fused_gemm12(
    const float* __restrict__ x, const float* __restrict__ dinv,
    const float* __restrict__ W1, const float* __restrict__ b1,
    const float* __restrict__ W2, float* __restrict__ out, int n) {
    constexpr int NT = 32, NTp = 36;
    __shared__ float Xs[64 * NTp];    // 9.2 KB
    __shared__ float Hs[100 * NTp];   // 14.4 KB
    int blockBase = blockIdx.x * NT;

    // ---- phase A: stage X transposed, node-fast ----
    for (int it = threadIdx.x; it < NT * 16; it += 256) {
        int node = it % NT;
        int kv = it / NT;
        int gn = blockBase + node;
        float4 v = make_float4(0.f, 0.f, 0.f, 0.f);
        if (gn < n) v = *(const float4*)&x[(size_t)gn * 64 + kv * 4];
        Xs[(kv * 4 + 0) * NTp + node] = v.x;
        Xs[(kv * 4 + 1) * NTp + node] = v.y;
        Xs[(kv * 4 + 2) * NTp + node] = v.z;
        Xs[(kv * 4 + 3) * NTp + node] = v.w;
    }
    __syncthreads();

    // ---- phase B: K=64, M=100, NTILES = 8*25 = 200 ----
    if (threadIdx.x < 200) {
        int ng = threadIdx.x / 25, mq = threadIdx.x % 25;
        int n0 = ng * 4, m0 = mq * 4;
        float acc[4][4] = {};
#pragma unroll 4
        for (int k = 0; k < 64; ++k) {
            float4 xv = *(const float4*)&Xs[k * NTp + n0];
            float4 wv = *(const float4*)&W1[k * 100 + m0];
            acc[0][0] = fmaf(xv.x, wv.x, acc[0][0]); acc[0][1] = fmaf(xv.x, wv.y, acc[0][1]);
            acc[0][2] = fmaf(xv.x, wv.z, acc[0][2]); acc[0][3] = fmaf(xv.x, wv.w, acc[0][3]);
            acc[1][0] = fmaf(xv.y, wv.x, acc[1][0]); acc[1][1] = fmaf(xv.y, wv.y, acc[1][1]);
            acc[1][2] = fmaf(xv.y, wv.z, acc[1][2]); acc[1][3] = fmaf(xv.y, wv.w, acc[1][3]);
            acc[2][0] = fmaf(xv.z, wv.x, acc[2][0]); acc[2][1] = fmaf(xv.z, wv.y, acc[2][1]);
            acc[2][2] = fmaf(xv.z, wv.z, acc[2][2]); acc[2][3] = fmaf(xv.z, wv.w, acc[2][3]);
            acc[3][0] = fmaf(xv.w, wv.x, acc[3][0]); acc[3][1] = fmaf(xv.w, wv.y, acc[3][1]);
            acc[3][2] = fmaf(xv.w, wv.z, acc[3][2]); acc[3][3] = fmaf(xv.w, wv.w, acc[3][3]);
        }
        float4 bb = *(const float4*)&b1[m0];
        float bv[4] = {bb.x, bb.y, bb.z, bb.w};
#pragma unroll
        for (int j = 0; j < 4; ++j)
#pragma unroll
            for (int i = 0; i < 4; ++i)
                Hs[(m0 + i) * NTp + n0 + j] = fmaxf(acc[j][i] + bv[i], 0.0f);
    }
    __syncthreads();

    // ---- phase C: K=100, M=50 (Mp=52, MQ=13), NTILES = 8*13 = 104 ----
    if (threadIdx.x < 104) {
        int ng = threadIdx.x / 13, mq = threadIdx.x % 13;
        int n0 = ng * 4, m0 = mq * 4;
        bool full = (m0 + 3 < 50);
        float acc[4][4] = {};
#pragma unroll 2
        for (int k = 0; k < 100; ++k) {
            float4 xv = *(const float4*)&Hs[k * NTp + n0];
            float4 wv;
            if (full) {
                float2 wa = *(const float2*)&W2[k * 50 + m0];
                float2 wb = *(const float2*)&W2[k * 50 + m0 + 2];
                wv = make_float4(wa.x, wa.y, wb.x, wb.y);
            } else {
                float2 wa = *(const float2*)&W2[k * 50 + 48];
                wv = make_float4(wa.x, wa.y, 0.f, 0.f);
            }
            acc[0][0] = fmaf(xv.x, wv.x, acc[0][0]); acc[0][1] = fmaf(xv.x, wv.y, acc[0][1]);
            acc[0][2] = fmaf(xv.x, wv.z, acc[0][2]); acc[0][3] = fmaf(xv.x, wv.w, acc[0][3]);
            acc[1][0] = fmaf(xv.y, wv.x, acc[1][0]); acc[1][1] = fmaf(xv.y, wv.y, acc[1][1]);
            acc[1][2] = fmaf(xv.y, wv.z, acc[1][2]); acc[1][3] = fmaf(xv.y, wv.w, acc[1][3]);
            acc[2][0] = fmaf(xv.z, wv.x, acc[2][0]); acc[2][1] = fmaf(xv.z, wv.y, acc[2][1]);
            acc[2][2] = fmaf(xv.z, wv.z, acc[2][2]); acc[2][3] = fmaf(xv.z, wv.w, acc[2][3]);
            acc[3][0] = fmaf(xv.w, wv.x, acc[3][0]); acc[3][1] = fmaf(xv.w, wv.y, acc[3][1]);
            acc[3][2] = fmaf(xv.w, wv.z, acc[3][2]); acc[3][3] = fmaf(xv.w, wv.w, acc[3][3]);
        }
#pragma unroll
        for (int j = 0; j < 4; ++j) {
            int node = blockBase + n0 + j;
            if (node < n) {
                float dv = dinv[node];
                if (full) {
                    float4 r = make_float4(acc[j][0] * dv, acc[j][1] * dv,
                                           acc[j][2] * dv, acc[j][3] * dv);
                    *(float4*)&out[(size_t)node * 64 + m0] = r;
                } else {
                    out[(size_t)node * 64 + 48] = acc[j][0] * dv;
                    out[(size_t)node * 64 + 49] = acc[j][1] * dv;
                }
            }
        }
    }
}

// ---------------- register-tiled GEMM (R7 proven, for layer-3 transform) ----------------
template <int K, int M, int NT, int XS, int OS, bool SCALE, bool BIAS_RELU>
__global__ __launch_bounds__(256) void gemm_tiled(
    const float* __restrict__ x, const float* __restrict__ W,
    const float* __restrict__ dinv, const float* __restrict__ b,
    float* __restrict__ out, int n) {
    static_assert(NT % 4 == 0 && K % 2 == 0 && XS % 16 == 0 && OS % 4 == 0, "");
    constexpr int Mp  = (M + 3) & ~3;
    constexpr int MQ  = Mp / 4;
    constexpr int NTp = NT + 4;
    constexpr int NTILES = (NT / 4) * MQ;
    static_assert(NTILES <= 256, "");

    __shared__ float Xs[K * NTp];
    __shared__ float Ws[K * Mp];

    if constexpr (M % 4 == 0) {
        for (int i = threadIdx.x; i < K * M / 4; i += 256)
            ((float4*)Ws)[i] = ((const float4*)W)[i];
    } else if constexpr (M % 2 == 0) {
        constexpr int C2 = Mp / 2;
        for (int i = threadIdx.x; i < K * C2; i += 256) {
            int r = i / C2, c = i - r * C2;
            float2 v;
            if (c * 2 + 1 < M)      v = *(const float2*)&W[r * M + c * 2];
            else if (c * 2 < M)     v = make_float2(W[r * M + c * 2], 0.0f);
            else                    v = make_float2(0.0f, 0.0f);
            *(float2*)&Ws[r * Mp + c * 2] = v;
        }
    } else {
        for (int i = threadIdx.x; i < K * Mp; i += 256) {
            int r = i / Mp, c = i - r * Mp;
            Ws[i] = (c < M) ? W[r * M + c] : 0.0f;
        }
    }

    int nodeBase = blockIdx.x * NT;
    constexpr int KV = (K % 4 == 0) ? 4 : 2;
    for (int it = threadIdx.x; it < NT * (K / KV); it += 256) {
        int node = it % NT;
        int kv = it / NT;
        int gn = nodeBase + node;
        if constexpr (KV == 4) {
            float4 v = make_float4(0.f, 0.f, 0.f, 0.f);
            if (gn < n) v = *(const float4*)&x[(size_t)gn * XS + kv * 4];
            Xs[(kv * 4 + 0) * NTp + node] = v.x;
            Xs[(kv * 4 + 1) * NTp + node] = v.y;
            Xs[(kv * 4 + 2) * NTp + node] = v.z;
            Xs[(kv * 4 + 3) * NTp + node] = v.w;
        } else {
            float2 v = make_float2(0.f, 0.f);
            if (gn < n) v = *(const float2*)&x[(size_t)gn * XS + kv * 2];
            Xs[(kv * 2 + 0) * NTp + node] = v.x;
            Xs[(kv * 2 + 1) * NTp + node] = v.y;
        }
    }
    __syncthreads();

    int t = threadIdx.x;
    if (t >= NTILES) return;
    int ng = t / MQ, mq = t - ng * MQ;
    int n0 = ng * 4;
    int m0 = mq * 4;

    float acc[4][4];
#pragma unroll
    for (int j = 0; j < 4; ++j)
#pragma unroll
        for (int i = 0; i < 4; ++i) acc[j][i] = 0.0f;

#pragma unroll 4
    for (int k = 0; k < K; ++k) {
        float4 xv = *(const float4*)&Xs[k * NTp + n0];
        float4 wv = *(const float4*)&Ws[k * Mp + m0];
        acc[0][0] = fmaf(xv.x, wv.x, acc[0][0]); acc[0][1] = fmaf(xv.x, wv.y, acc[0][1]);
        acc[0][2] = fmaf(xv.x, wv.z, acc[0][2]); acc[0][3] = fmaf(xv.x, wv.w, acc[0][3]);
        acc[1][0] = fmaf(xv.y, wv.x, acc[1][0]); acc[1][1] = fmaf(xv.y, wv.y, acc[1][1]);
        acc[1][2] = fmaf(xv.y, wv.z, acc[1][2]); acc[1][3] = fmaf(xv.y, wv.w, acc[1][3]);
        acc[2][0] = fmaf(xv.z, wv.x, acc[2][0]); acc[2][1] = fmaf(xv.z, wv.y, acc[2][1]);
        acc[2][2] = fmaf(xv.z, wv.z, acc[2][2]); acc[2][3] = fmaf(xv.z, wv.w, acc[2][3]);
        acc[3][0] = fmaf(xv.w, wv.x, acc[3][0]); acc[3][1] = fmaf(xv.w, wv.y, acc[3][1]);
        acc[3][2] = fmaf(xv.w, wv.z, acc[3][2]); acc[3][3] = fmaf(xv.w, wv.w, acc[3][3]);
    }

#pragma unroll
    for (int j = 0; j < 4; ++j) {
        int nd = nodeBase + n0 + j;
        if (nd >= n) continue;
        float dv = SCALE ? dinv[nd] : 1.0f;
        if (m0 + 3 < M) {
            float4 r = make_float4(acc[j][0], acc[j][1], acc[j][2], acc[j][3]);
            if (SCALE) r = mul4s(r, dv);
            if (BIAS_RELU) {
                r.x = fmaxf(r.x + b[m0 + 0], 0.0f);
                r.y = fmaxf(r.y + b[m0 + 1], 0.0f);
                r.z = fmaxf(r.z + b[m0 + 2], 0.0f);
                r.w = fmaxf(r.w + b[m0 + 3], 0.0f);
            }
            *(float4*)&out[(size_t)nd * OS + m0] = r;
        } else {
#pragma unroll
            for (int i = 0; i < 4; ++i) {
                int m = m0 + i;
                if (m < M) {
                    float r = acc[j][i];
                    if (SCALE) r *= dv;
                    if (BIAS_RELU) r = fmaxf(r + b[m], 0.0f);
                    out[(size_t)nd * OS + m] = r;
                }
            }
        }
    }
}

// ---------------- fused layer-3 aggregate + 3-layer MLP head (R7 proven) ----------------
__global__ __launch_bounds__(256) void agg3_mlp(
    const float* __restrict__ s, const int* __restrict__ offs,
    const int* __restrict__ csr, const float* __restrict__ dinv,
    const float* __restrict__ bg,
    const float* __restrict__ Wl1, const float* __restrict__ bl1,
    const float* __restrict__ Wl2, const float* __restrict__ bl2,
    const float* __restrict__ Wl3, const float* __restrict__ bl3,
    float* __restrict__ out, int n) {
    constexpr int M = 25, S = 32, LPN = 8;
    __shared__ float W1s[625], W2s[250], W3s[10], b1s[25], b2s[10];
    __shared__ float accs[32 * 26];
    __shared__ float b3s;

    for (int i = threadIdx.x; i < 625; i += 256) W1s[i] = Wl1[i];
    for (int i = threadIdx.x; i < 250; i += 256) W2s[i] = Wl2[i];
    if (threadIdx.x < 10) { W3s[threadIdx.x] = Wl3[threadIdx.x]; b2s[threadIdx.x] = bl2[threadIdx.x]; }
    if (threadIdx.x < 25) b1s[threadIdx.x] = bl1[threadIdx.x];
    if (threadIdx.x == 0) b3s = bl3[0];

    int lane = threadIdx.x % LPN;
    int nl   = threadIdx.x / LPN;
    int node = blockIdx.x * 32 + nl;
    int f0 = lane * 4;

    if (node < n) {
        bool active = f0 < M;
        float dv = dinv[node];
        float4 z = make_float4(0.f, 0.f, 0.f, 0.f);
        float4 acc0 = z, acc1 = z, acc2 = z, acc3 = z;
        if (active) acc0 = *(const float4*)&s[(size_t)node * S + f0];

        int e0 = offs[node], e1 = offs[node + 1];
        int e = e0;
        for (; e + 4 <= e1; e += 4) {
            int i0 = csr[e], i1 = csr[e + 1], i2 = csr[e + 2], i3 = csr[e + 3];
            float4 v0 = z, v1 = z, v2 = z, v3 = z;
            if (active) {
                v0 = *(const float4*)&s[(size_t)i0 * S + f0];
                v1 = *(const float4*)&s[(size_t)i1 * S + f0];
                v2 = *(const float4*)&s[(size_t)i2 * S + f0];
                v3 = *(const float4*)&s[(size_t)i3 * S + f0];
            }
            acc0 = add4(acc0, v0); acc1 = add4(acc1, v1);
            acc2 = add4(acc2, v2); acc3 = add4(acc3, v3);
        }
        for (; e < e1; ++e) {
            int sid = csr[e];
            float4 v = active ? *(const float4*)&s[(size_t)sid * S + f0] : z;
            acc0 = add4(acc0, v);
        }
        float4 acc = add4(add4(acc0, acc1), add4(acc2, acc3));

        if (active) {
            float4 r = mul4s(acc, dv);
            if (f0 + 0 < M) accs[nl * 26 + f0 + 0] = fmaxf(r.x + bg[f0 + 0], 0.0f);
            if (f0 + 1 < M) accs[nl * 26 + f0 + 1] = fmaxf(r.y + bg[f0 + 1], 0.0f);
            if (f0 + 2 < M) accs[nl * 26 + f0 + 2] = fmaxf(r.z + bg[f0 + 2], 0.0f);
            if (f0 + 3 < M) accs[nl * 26 + f0 + 3] = fmaxf(r.w + bg[f0 + 3], 0.0f);
        }
    }
    __syncthreads();

    if (threadIdx.x < 32) {
        int nd = blockIdx.x * 32 + threadIdx.x;
        if (nd < n) {
            const float* xr = &accs[threadIdx.x * 26];
            float h1[25];
#pragma unroll
            for (int m = 0; m < 25; ++m) {
                float a = b1s[m];
#pragma unroll
                for (int k = 0; k < 25; ++k) a = fmaf(xr[k], W1s[k * 25 + m], a);
                h1[m] = fmaxf(a, 0.0f);
            }
            float h2[10];
#pragma unroll
            for (int m = 0; m < 10; ++m) {
                float a = b2s[m];
#pragma unroll
                for (int k = 0; k < 25; ++k) a = fmaf(h1[k], W2s[k * 10 + m], a);
                h2[m] = fmaxf(a, 0.0f);
            }
            float a = b3s;
#pragma unroll
            for (int k = 0; k < 10; ++k) a = fmaf(h2[k], W3s[k], a);
            out[nd] = fmaxf(a, 0.0f);
        }
    }
}

// ---------------- launch ----------------

extern "C" void kernel_launch(void* const* d_in, const int* in_sizes, int n_in,
                              void* d_out, int out_size, void* d_ws, size_t ws_size,
                              hipStream_t stream) {
    const float* x0  = (const float*)d_in[0];
    const float* W1  = (const float*)d_in[1];
    const float* b1  = (const float*)d_in[2];
    const float* W2  = (const float*)d_in[3];
    const float* b2  = (const float*)d_in[4];
    const float* W3  = (const float*)d_in[5];
    const float* b3  = (const float*)d_in[6];
    const float* Wl1 = (const float*)d_in[7];
    const float* bl1 = (const float*)d_in[8];
    const float* Wl2 = (const float*)d_in[9];
    const float* bl2 = (const float*)d_in[10];
    const float* Wl3 = (const float*)d_in[11];
    const float* bl3 = (const float*)d_in[12];
    const int*   edge = (const int*)d_in[13];

    int n  = in_sizes[0] / 64;      // 100000
    int ne = in_sizes[13] / 2;      // 1000000
    const int* esrc = edge;
    const int* edst = edge + ne;

    char* ws = (char*)d_ws;
    auto alloc = [&](size_t bytes) {
        char* p = ws;
        ws += (bytes + 255) & ~(size_t)255;
        return p;
    };
    int*   offs       = (int*)alloc((size_t)(n + 1) * 4);
    int*   bucketCur  = (int*)alloc(NBUCK * 4);
    int*   bucketBase = (int*)alloc(NBUCK * 4);
    int*   csr        = (int*)alloc((size_t)ne * 4);
    float* dinv       = (float*)alloc((size_t)n * 4);
    float* bufA       = (float*)alloc((size_t)n * 64 * 4);   // stride-64
    float* bufD       = (float*)alloc((size_t)n * 64 * 4);   // stride-64
    // aliases: pairs consumed by bucket_csr before agg1 writes bufA;
    // bufE (agg2 out) aliases bufA (dead after fused_gemm12 reads it);
    // bufC (gemm3 out, stride 32) aliases bufD-front (dead after agg2 reads it).
    int*   pairs = (int*)bufA;
    float* bufE  = bufA;
    float* bufC  = bufD;
    (void)ws_size; (void)n_in; (void)out_size;

    int nbuckets = (n + (1 << BSHIFT) - 1) >> BSHIFT;   // 196
    int nblocks32 = (n + 31) / 32;

    // CSR + dinv (4 dispatches)
    zero_ints<<<1, 256, 0, stream>>>(bucketCur, NBUCK);
    partition_edges<<<(ne + 256 * EPT - 1) / (256 * EPT), 256, 0, stream>>>(
        esrc, edst, bucketCur, pairs, ne);
    scan_buckets<<<1, 256, 0, stream>>>(bucketCur, bucketBase, offs, n, ne, nbuckets);
    bucket_csr<<<nbuckets, 256, 0, stream>>>(pairs, bucketCur, bucketBase, offs, dinv, csr, n);

    // agg1: bufA = ÂX (stride 64)
    aggregate<64, 64, 16, true, false><<<(n + 15) / 16, 256, 0, stream>>>(
        x0, offs, csr, dinv, nullptr, bufA, n);

    // fused gemm1+gemm2 (gather-free): bufD = (relu(bufA@W1+b1)@W2)*dinv (stride 64, cols 0..49)
    fused_gemm12<<<nblocks32, 256, 0, stream>>>(bufA, dinv, W1, b1, W2, bufD, n);

    // agg2: bufE = relu(dinv*agg(bufD)+b2) (stride 64)  [bufE aliases bufA]
    aggregate<50, 64, 16, false, true><<<(n + 15) / 16, 256, 0, stream>>>(
        bufD, offs, csr, dinv, b2, bufE, n);

    // gemm3: bufC = (bufE@W3)*dinv (stride 32)  [bufC aliases bufD]
    gemm_tiled<50, 25, 144, 64, 32, true, false><<<(n + 143) / 144, 256, 0, stream>>>(
        bufE, W3, dinv, nullptr, bufC, n);

    // agg3 + MLP head -> d_out
    agg3_mlp<<<nblocks32, 256, 0, stream>>>(
        bufC, offs, csr, dinv, b3, Wl1, bl1, Wl2, bl2, Wl3, bl3, (float*)d_out, n);
}

// Round 11
// 294.941 us; speedup vs baseline: 1.3211x; 1.3211x over previous
//
#include <hip/hip_runtime.h>
#include <hip/hip_fp16.h>
#include <cstdint>

constexpr int BSHIFT = 9;               // 512 nodes per bucket
constexpr int NBUCK  = 256;             // max buckets (covers 131072 nodes)
constexpr int BUCKET_CAP = 6144;        // slot capacity; E/bucket ~ Poisson(5102), 14 sigma

struct alignas(16) H8 { __half2 a, b, c, d; };
struct alignas(8)  H4 { __half2 a, b; };

__device__ __forceinline__ float4 add4(float4 a, float4 b) {
    return make_float4(a.x + b.x, a.y + b.y, a.z + b.z, a.w + b.w);
}
__device__ __forceinline__ float4 mul4s(float4 a, float s) {
    return make_float4(a.x * s, a.y * s, a.z * s, a.w * s);
}
__device__ __forceinline__ void acc_h8(float4& A0, float4& A1, const H8 v, float s) {
    float2 f0 = __half22float2(v.a), f1 = __half22float2(v.b);
    float2 f2 = __half22float2(v.c), f3 = __half22float2(v.d);
    A0.x = fmaf(f0.x, s, A0.x); A0.y = fmaf(f0.y, s, A0.y);
    A0.z = fmaf(f1.x, s, A0.z); A0.w = fmaf(f1.y, s, A0.w);
    A1.x = fmaf(f2.x, s, A1.x); A1.y = fmaf(f2.y, s, A1.y);
    A1.z = fmaf(f3.x, s, A1.z); A1.w = fmaf(f3.y, s, A1.w);
}

// ---------------- CSR build (bucketed, LDS-local, packed pairs) ----------------

__global__ void zero_ints(int* __restrict__ p, int n) {
    int i = blockIdx.x * blockDim.x + threadIdx.x;
    if (i < n) p[i] = 0;
}

constexpr int EPT = 16;  // edges per thread; chunk = 4096
__global__ __launch_bounds__(256) void partition_edges(
    const int* __restrict__ src, const int* __restrict__ dst,
    int* __restrict__ bucketCur, int* __restrict__ pairs, int ne) {
    __shared__ int lcnt[NBUCK];
    __shared__ int lbase[NBUCK];
    int base = blockIdx.x * (256 * EPT);
    if (threadIdx.x < NBUCK) lcnt[threadIdx.x] = 0;
    __syncthreads();
    int2 ed[EPT];
    int  rnk[EPT];
#pragma unroll
    for (int j = 0; j < EPT; ++j) {
        int e = base + j * 256 + threadIdx.x;
        if (e < ne) {
            int d = dst[e];
            ed[j] = make_int2(src[e], d);
            rnk[j] = atomicAdd(&lcnt[d >> BSHIFT], 1);
        } else {
            ed[j].y = -1;
        }
    }
    __syncthreads();
    if (threadIdx.x < NBUCK) {
        int c = lcnt[threadIdx.x];
        lbase[threadIdx.x] = c ? atomicAdd(&bucketCur[threadIdx.x], c) : 0;
    }
    __syncthreads();
#pragma unroll
    for (int j = 0; j < EPT; ++j) {
        if (ed[j].y >= 0) {
            int b = ed[j].y >> BSHIFT;
            int p = lbase[b] + rnk[j];
            if (p < BUCKET_CAP)
                pairs[(size_t)b * BUCKET_CAP + p] =
                    (ed[j].x << BSHIFT) | (ed[j].y & ((1 << BSHIFT) - 1));
        }
    }
}

__global__ void scan_buckets(const int* __restrict__ bucketCnt, int* __restrict__ bucketBase,
                             int* __restrict__ offs, int n, int ne, int nbuckets) {
    __shared__ int tmp[256];
    int c = (threadIdx.x < (unsigned)nbuckets) ? bucketCnt[threadIdx.x] : 0;
    tmp[threadIdx.x] = c;
    __syncthreads();
    for (int off = 1; off < 256; off <<= 1) {
        int t = (threadIdx.x >= (unsigned)off) ? tmp[threadIdx.x - off] : 0;
        __syncthreads();
        tmp[threadIdx.x] += t;
        __syncthreads();
    }
    if (threadIdx.x < (unsigned)nbuckets) bucketBase[threadIdx.x] = tmp[threadIdx.x] - c;
    if (threadIdx.x == 0) offs[n] = ne;
}

__global__ __launch_bounds__(256) void bucket_csr(
    const int* __restrict__ pairs, const int* __restrict__ bucketCnt,
    const int* __restrict__ bucketBase, int* __restrict__ offs,
    float* __restrict__ dinv, int* __restrict__ csr, int n) {
    constexpr int BN = 1 << BSHIFT;  // 512
    __shared__ int hist[BN];
    __shared__ int cur[BN];
    __shared__ int tmp[256];
    int b = blockIdx.x;
    int cnt  = bucketCnt[b];
    int base = bucketBase[b];
    const int* pb = pairs + (size_t)b * BUCKET_CAP;
    int nodeLo = b << BSHIFT;

    hist[threadIdx.x] = 0;
    hist[threadIdx.x + 256] = 0;
    __syncthreads();
    for (int e = threadIdx.x; e < cnt; e += 256)
        atomicAdd(&hist[pb[e] & (BN - 1)], 1);
    __syncthreads();

    int l0 = 2 * threadIdx.x, l1 = l0 + 1;
    int h0 = hist[l0], h1 = hist[l1];
    tmp[threadIdx.x] = h0 + h1;
    __syncthreads();
    for (int off = 1; off < 256; off <<= 1) {
        int t = (threadIdx.x >= (unsigned)off) ? tmp[threadIdx.x - off] : 0;
        __syncthreads();
        tmp[threadIdx.x] += t;
        __syncthreads();
    }
    int e0 = tmp[threadIdx.x] - (h0 + h1);
    int e1 = e0 + h0;
    int g0 = nodeLo + l0, g1 = nodeLo + l1;
    if (g0 < n) { offs[g0] = base + e0; dinv[g0] = rsqrtf((float)(h0 + 1)); }
    if (g1 < n) { offs[g1] = base + e1; dinv[g1] = rsqrtf((float)(h1 + 1)); }
    cur[l0] = e0;
    cur[l1] = e1;
    __syncthreads();

    for (int e = threadIdx.x; e < cnt; e += 256) {
        int p = pb[e];
        int pos = atomicAdd(&cur[p & (BN - 1)], 1);
        csr[base + pos] = ((unsigned)p) >> BSHIFT;
    }
}

// ---------------- fp32 -> fp16 streaming convert (16 float4s per node row) ----------------
__global__ void cvt_f32_f16(const float* __restrict__ x, __half* __restrict__ o, int n4) {
    int i = blockIdx.x * blockDim.x + threadIdx.x;
    if (i < n4) {
        float4 v = ((const float4*)x)[i];
        H4 h;
        h.a = __floats2half2_rn(v.x, v.y);
        h.b = __floats2half2_rn(v.z, v.w);
        ((H4*)o)[i] = h;
    }
}

// ---------------- fp16-gather aggregation: 16B(8 halves)/lane, unroll 4 ----------------
// MH = useful halves per row, SH = row stride in halves, OSF = output stride in floats.
// fp32 accumulate; same proven unroll-4 loop shape as the R7 fp32 aggregate.
template <int MH, int SH, int LPN, bool SCALE_SRC, bool RELU_BIAS, int OSF>
__global__ __launch_bounds__(256) void aggregate_h(
    const __half* __restrict__ s, const int* __restrict__ offs,
    const int* __restrict__ csr, const float* __restrict__ dinv,
    const float* __restrict__ b, float* __restrict__ out, int n) {
    int lane = threadIdx.x % LPN;
    int node = blockIdx.x * (256 / LPN) + threadIdx.x / LPN;
    if (node >= n) return;
    int f0 = lane * 8;
    if (f0 >= MH) return;
    float dv = dinv[node];

    float4 z = make_float4(0.f, 0.f, 0.f, 0.f);
    float4 a00 = z, a01 = z, a10 = z, a11 = z, a20 = z, a21 = z, a30 = z, a31 = z;
    {
        H8 sv = *(const H8*)&s[(size_t)node * SH + f0];
        acc_h8(a00, a01, sv, SCALE_SRC ? dv : 1.0f);
    }
    int e0 = offs[node], e1 = offs[node + 1];
    int e = e0;
    for (; e + 4 <= e1; e += 4) {
        int i0 = csr[e], i1 = csr[e + 1], i2 = csr[e + 2], i3 = csr[e + 3];
        H8 v0 = *(const H8*)&s[(size_t)i0 * SH + f0];
        H8 v1 = *(const H8*)&s[(size_t)i1 * SH + f0];
        H8 v2 = *(const H8*)&s[(size_t)i2 * SH + f0];
        H8 v3 = *(const H8*)&s[(size_t)i3 * SH + f0];
        float s0 = SCALE_SRC ? dinv[i0] : 1.0f;
        float s1 = SCALE_SRC ? dinv[i1] : 1.0f;
        float s2 = SCALE_SRC ? dinv[i2] : 1.0f;
        float s3 = SCALE_SRC ? dinv[i3] : 1.0f;
        acc_h8(a00, a01, v0, s0);
        acc_h8(a10, a11, v1, s1);
        acc_h8(a20, a21, v2, s2);
        acc_h8(a30, a31, v3, s3);
    }
    for (; e < e1; ++e) {
        int sid = csr[e];
        H8 v = *(const H8*)&s[(size_t)sid * SH + f0];
        acc_h8(a00, a01, v, SCALE_SRC ? dinv[sid] : 1.0f);
    }
    float4 A0 = add4(add4(a00, a10), add4(a20, a30));
    float4 A1 = add4(add4(a01, a11), add4(a21, a31));
    A0 = mul4s(A0, dv);
    A1 = mul4s(A1, dv);

    float v[8] = {A0.x, A0.y, A0.z, A0.w, A1.x, A1.y, A1.z, A1.w};
    if (RELU_BIAS) {
#pragma unroll
        for (int i = 0; i < 8; ++i)
            if (f0 + i < MH) v[i] = fmaxf(v[i] + b[f0 + i], 0.0f);
    }
    float* o = &out[(size_t)node * OSF + f0];
    if (f0 + 7 < MH) {
        *(float4*)o      = make_float4(v[0], v[1], v[2], v[3]);
        *(float4*)&o[4]  = make_float4(v[4], v[5], v[6], v[7]);
    } else {
#pragma unroll
        for (int i = 0; i < 8; ++i)
            if (f0 + i < MH) o[i] = v[i];
    }
}

// ---------------- register-tiled GEMM (R7 proven; optional fp16 output) ----------------
template <int K, int M, int NT, int XS, int OS, bool SCALE, bool BIAS_RELU, bool OUT16>
__global__ __launch_bounds__(256) void gemm_tiled(
    const float* __restrict__ x, const float* __restrict__ W,
    const float* __restrict__ dinv, const float* __restrict__ b,
    void* __restrict__ outv, int n) {
    static_assert(NT % 4 == 0 && K % 2 == 0 && XS % 16 == 0 && OS % 4 == 0, "");
    constexpr int Mp  = (M + 3) & ~3;
    constexpr int MQ  = Mp / 4;
    constexpr int NTp = NT + 4;
    constexpr int NTILES = (NT / 4) * MQ;
    static_assert(NTILES <= 256, "");

    __shared__ float Xs[K * NTp];
    __shared__ float Ws[K * Mp];

    if constexpr (M % 4 == 0) {
        for (int i = threadIdx.x; i < K * M / 4; i += 256)
            ((float4*)Ws)[i] = ((const float4*)W)[i];
    } else if constexpr (M % 2 == 0) {
        constexpr int C2 = Mp / 2;
        for (int i = threadIdx.x; i < K * C2; i += 256) {
            int r = i / C2, c = i - r * C2;
            float2 v;
            if (c * 2 + 1 < M)      v = *(const float2*)&W[r * M + c * 2];
            else if (c * 2 < M)     v = make_float2(W[r * M + c * 2], 0.0f);
            else                    v = make_float2(0.0f, 0.0f);
            *(float2*)&Ws[r * Mp + c * 2] = v;
        }
    } else {
        for (int i = threadIdx.x; i < K * Mp; i += 256) {
            int r = i / Mp, c = i - r * Mp;
            Ws[i] = (c < M) ? W[r * M + c] : 0.0f;
        }
    }

    int nodeBase = blockIdx.x * NT;
    constexpr int KV = (K % 4 == 0) ? 4 : 2;
    for (int it = threadIdx.x; it < NT * (K / KV); it += 256) {
        int node = it % NT;
        int kv = it / NT;
        int gn = nodeBase + node;
        if constexpr (KV == 4) {
            float4 v = make_float4(0.f, 0.f, 0.f, 0.f);
            if (gn < n) v = *(const float4*)&x[(size_t)gn * XS + kv * 4];
            Xs[(kv * 4 + 0) * NTp + node] = v.x;
            Xs[(kv * 4 + 1) * NTp + node] = v.y;
            Xs[(kv * 4 + 2) * NTp + node] = v.z;
            Xs[(kv * 4 + 3) * NTp + node] = v.w;
        } else {
            float2 v = make_float2(0.f, 0.f);
            if (gn < n) v = *(const float2*)&x[(size_t)gn * XS + kv * 2];
            Xs[(kv * 2 + 0) * NTp + node] = v.x;
            Xs[(kv * 2 + 1) * NTp + node] = v.y;
        }
    }
    __syncthreads();

    int t = threadIdx.x;
    if (t >= NTILES) return;
    int ng = t / MQ, mq = t - ng * MQ;
    int n0 = ng * 4;
    int m0 = mq * 4;

    float acc[4][4];
#pragma unroll
    for (int j = 0; j < 4; ++j)
#pragma unroll
        for (int i = 0; i < 4; ++i) acc[j][i] = 0.0f;

#pragma unroll 4
    for (int k = 0; k < K; ++k) {
        float4 xv = *(const float4*)&Xs[k * NTp + n0];
        float4 wv = *(const float4*)&Ws[k * Mp + m0];
        acc[0][0] = fmaf(xv.x, wv.x, acc[0][0]); acc[0][1] = fmaf(xv.x, wv.y, acc[0][1]);
        acc[0][2] = fmaf(xv.x, wv.z, acc[0][2]); acc[0][3] = fmaf(xv.x, wv.w, acc[0][3]);
        acc[1][0] = fmaf(xv.y, wv.x, acc[1][0]); acc[1][1] = fmaf(xv.y, wv.y, acc[1][1]);
        acc[1][2] = fmaf(xv.y, wv.z, acc[1][2]); acc[1][3] = fmaf(xv.y, wv.w, acc[1][3]);
        acc[2][0] = fmaf(xv.z, wv.x, acc[2][0]); acc[2][1] = fmaf(xv.z, wv.y, acc[2][1]);
        acc[2][2] = fmaf(xv.z, wv.z, acc[2][2]); acc[2][3] = fmaf(xv.z, wv.w, acc[2][3]);
        acc[3][0] = fmaf(xv.w, wv.x, acc[3][0]); acc[3][1] = fmaf(xv.w, wv.y, acc[3][1]);
        acc[3][2] = fmaf(xv.w, wv.z, acc[3][2]); acc[3][3] = fmaf(xv.w, wv.w, acc[3][3]);
    }

#pragma unroll
    for (int j = 0; j < 4; ++j) {
        int nd = nodeBase + n0 + j;
        if (nd >= n) continue;
        float dv = SCALE ? dinv[nd] : 1.0f;
        float r[4];
#pragma unroll
        for (int i = 0; i < 4; ++i) {
            r[i] = acc[j][i];
            if (SCALE) r[i] *= dv;
            if (BIAS_RELU) r[i] = fmaxf(r[i] + b[m0 + i], 0.0f);
        }
        if constexpr (OUT16) {
            __half* oh = (__half*)outv;
            if (m0 + 3 < M) {
                H4 h;
                h.a = __floats2half2_rn(r[0], r[1]);
                h.b = __floats2half2_rn(r[2], r[3]);
                *(H4*)&oh[(size_t)nd * OS + m0] = h;
            } else {
#pragma unroll
                for (int i = 0; i < 4; ++i)
                    if (m0 + i < M) oh[(size_t)nd * OS + m0 + i] = __float2half_rn(r[i]);
            }
        } else {
            float* of = (float*)outv;
            if (m0 + 3 < M) {
                *(float4*)&of[(size_t)nd * OS + m0] = make_float4(r[0], r[1], r[2], r[3]);
            } else {
#pragma unroll
                for (int i = 0; i < 4; ++i)
                    if (m0 + i < M) of[(size_t)nd * OS + m0 + i] = r[i];
            }
        }
    }
}

// ---------------- fused layer-3 aggregate (fp16 gather, 1 line/row) + MLP head ----------
// Block = 64 nodes, LPN=4 (8 halves/lane over stride-32 rows).
__global__ __launch_bounds__(256) void agg3_mlp_h(
    const __half* __restrict__ s, const int* __restrict__ offs,
    const int* __restrict__ csr, const float* __restrict__ dinv,
    const float* __restrict__ bg,
    const float* __restrict__ Wl1, const float* __restrict__ bl1,
    const float* __restrict__ Wl2, const float* __restrict__ bl2,
    const float* __restrict__ Wl3, const float* __restrict__ bl3,
    float* __restrict__ out, int n) {
    constexpr int MH = 25, SH = 32, LPN = 4;
    __shared__ float W1s[625], W2s[250], W3s[10], b1s[25], b2s[10];
    __shared__ float accs[64 * 26];
    __shared__ float b3s;

    for (int i = threadIdx.x; i < 625; i += 256) W1s[i] = Wl1[i];
    for (int i = threadIdx.x; i < 250; i += 256) W2s[i] = Wl2[i];
    if (threadIdx.x < 10) { W3s[threadIdx.x] = Wl3[threadIdx.x]; b2s[threadIdx.x] = bl2[threadIdx.x]; }
    if (threadIdx.x < 25) b1s[threadIdx.x] = bl1[threadIdx.x];
    if (threadIdx.x == 0) b3s = bl3[0];

    int lane = threadIdx.x % LPN;
    int nl   = threadIdx.x / LPN;
    int node = blockIdx.x * 64 + nl;
    int f0 = lane * 8;

    if (node < n && f0 < MH) {
        float dv = dinv[node];
        float4 z = make_float4(0.f, 0.f, 0.f, 0.f);
        float4 a00 = z, a01 = z, a10 = z, a11 = z, a20 = z, a21 = z, a30 = z, a31 = z;
        {
            H8 sv = *(const H8*)&s[(size_t)node * SH + f0];
            acc_h8(a00, a01, sv, 1.0f);
        }
        int e0 = offs[node], e1 = offs[node + 1];
        int e = e0;
        for (; e + 4 <= e1; e += 4) {
            int i0 = csr[e], i1 = csr[e + 1], i2 = csr[e + 2], i3 = csr[e + 3];
            H8 v0 = *(const H8*)&s[(size_t)i0 * SH + f0];
            H8 v1 = *(const H8*)&s[(size_t)i1 * SH + f0];
            H8 v2 = *(const H8*)&s[(size_t)i2 * SH + f0];
            H8 v3 = *(const H8*)&s[(size_t)i3 * SH + f0];
            acc_h8(a00, a01, v0, 1.0f);
            acc_h8(a10, a11, v1, 1.0f);
            acc_h8(a20, a21, v2, 1.0f);
            acc_h8(a30, a31, v3, 1.0f);
        }
        for (; e < e1; ++e) {
            H8 v = *(const H8*)&s[(size_t)csr[e] * SH + f0];
            acc_h8(a00, a01, v, 1.0f);
        }
        float4 A0 = add4(add4(a00, a10), add4(a20, a30));
        float4 A1 = add4(add4(a01, a11), add4(a21, a31));
        float v[8] = {A0.x, A0.y, A0.z, A0.w, A1.x, A1.y, A1.z, A1.w};
#pragma unroll
        for (int i = 0; i < 8; ++i)
            if (f0 + i < MH)
                accs[nl * 26 + f0 + i] = fmaxf(dv * v[i] + bg[f0 + i], 0.0f);
    }
    __syncthreads();

    if (threadIdx.x < 64) {
        int nd = blockIdx.x * 64 + threadIdx.x;
        if (nd < n) {
            const float* xr = &accs[threadIdx.x * 26];
            float h1[25];
#pragma unroll
            for (int m = 0; m < 25; ++m) {
                float a = b1s[m];
#pragma unroll
                for (int k = 0; k < 25; ++k) a = fmaf(xr[k], W1s[k * 25 + m], a);
                h1[m] = fmaxf(a, 0.0f);
            }
            float h2[10];
#pragma unroll
            for (int m = 0; m < 10; ++m) {
                float a = b2s[m];
#pragma unroll
                for (int k = 0; k < 25; ++k) a = fmaf(h1[k], W2s[k * 10 + m], a);
                h2[m] = fmaxf(a, 0.0f);
            }
            float a = b3s;
#pragma unroll
            for (int k = 0; k < 10; ++k) a = fmaf(h2[k], W3s[k], a);
            out[nd] = fmaxf(a, 0.0f);
        }
    }
}

// ---------------- launch ----------------

extern "C" void kernel_launch(void* const* d_in, const int* in_sizes, int n_in,
                              void* d_out, int out_size, void* d_ws, size_t ws_size,
                              hipStream_t stream) {
    const float* x0  = (const float*)d_in[0];
    const float* W1  = (const float*)d_in[1];
    const float* b1  = (const float*)d_in[2];
    const float* W2  = (const float*)d_in[3];
    const float* b2  = (const float*)d_in[4];
    const float* W3  = (const float*)d_in[5];
    const float* b3  = (const float*)d_in[6];
    const float* Wl1 = (const float*)d_in[7];
    const float* bl1 = (const float*)d_in[8];
    const float* Wl2 = (const float*)d_in[9];
    const float* bl2 = (const float*)d_in[10];
    const float* Wl3 = (const float*)d_in[11];
    const float* bl3 = (const float*)d_in[12];
    const int*   edge = (const int*)d_in[13];

    int n  = in_sizes[0] / 64;      // 100000
    int ne = in_sizes[13] / 2;      // 1000000
    const int* esrc = edge;
    const int* edst = edge + ne;

    char* ws = (char*)d_ws;
    auto alloc = [&](size_t bytes) {
        char* p = ws;
        ws += (bytes + 255) & ~(size_t)255;
        return p;
    };
    int*    offs       = (int*)alloc((size_t)(n + 1) * 4);
    int*    bucketCur  = (int*)alloc(NBUCK * 4);
    int*    bucketBase = (int*)alloc(NBUCK * 4);
    int*    csr        = (int*)alloc((size_t)ne * 4);
    float*  dinv       = (float*)alloc((size_t)n * 4);
    float*  bufA       = (float*)alloc((size_t)n * 64 * 4);   // fp32 stride-64
    float*  bufB       = (float*)alloc((size_t)n * 112 * 4);  // fp32 stride-112
    __half* bufDh      = (__half*)alloc((size_t)n * 64 * 2);  // fp16 stride-64h (128B rows)
    // aliases (ordered lifetimes):
    //   pairs: in bufB[0..4.8MB), consumed by bucket_csr before gemm1 writes bufB
    //   x0h  : in bufB[4.8MB..17.6MB), written by cvt after bucket_csr, consumed by agg1
    //          before gemm1 writes bufB
    //   bufE (agg2 out, fp32 s64) aliases bufA (dead after gemm1 reads it)
    //   bufCh (gemm3 out, fp16 s32) aliases bufDh (dead after agg2 reads it)
    int*    pairs = (int*)bufB;
    __half* x0h   = (__half*)((char*)bufB + (size_t)NBUCK * BUCKET_CAP * 4);
    float*  bufE  = bufA;
    __half* bufCh = bufDh;
    (void)ws_size; (void)n_in; (void)out_size;

    int nbuckets = (n + (1 << BSHIFT) - 1) >> BSHIFT;   // 196

    // CSR + dinv (4 dispatches)
    zero_ints<<<1, 256, 0, stream>>>(bucketCur, NBUCK);
    partition_edges<<<(ne + 256 * EPT - 1) / (256 * EPT), 256, 0, stream>>>(
        esrc, edst, bucketCur, pairs, ne);
    scan_buckets<<<1, 256, 0, stream>>>(bucketCur, bucketBase, offs, n, ne, nbuckets);
    bucket_csr<<<nbuckets, 256, 0, stream>>>(pairs, bucketCur, bucketBase, offs, dinv, csr, n);

    // x0h = fp16(x0)  [n,64]
    cvt_f32_f16<<<(n * 16 + 255) / 256, 256, 0, stream>>>(x0, x0h, n * 16);

    // agg1 (fp16 gather, 2 lines/row): bufA = ÂX fp32 stride 64
    aggregate_h<64, 64, 8, true, false, 64><<<(n + 31) / 32, 256, 0, stream>>>(
        x0h, offs, csr, dinv, nullptr, bufA, n);

    // gemm1: bufB = relu(bufA@W1 + b1) fp32 stride 112
    gemm_tiled<64, 100, 40, 64, 112, false, true, false><<<(n + 39) / 40, 256, 0, stream>>>(
        bufA, W1, nullptr, b1, bufB, n);

    // gemm2: bufDh = (bufB@W2)*dinv fp16 stride 64h
    gemm_tiled<100, 50, 64, 112, 64, true, false, true><<<(n + 63) / 64, 256, 0, stream>>>(
        bufB, W2, dinv, nullptr, bufDh, n);

    // agg2 (fp16 gather, 2 lines/row): bufE = relu(dinv*agg(bufDh)+b2) fp32 stride 64
    aggregate_h<50, 64, 8, false, true, 64><<<(n + 31) / 32, 256, 0, stream>>>(
        bufDh, offs, csr, dinv, b2, bufE, n);

    // gemm3: bufCh = (bufE@W3)*dinv fp16 stride 32h (64B rows)
    gemm_tiled<50, 25, 144, 64, 32, true, false, true><<<(n + 143) / 144, 256, 0, stream>>>(
        bufE, W3, dinv, nullptr, bufCh, n);

    // agg3 (fp16 gather, 1 line/row) + MLP head -> d_out
    agg3_mlp_h<<<(n + 63) / 64, 256, 0, stream>>>(
        bufCh, offs, csr, dinv, b3, Wl1, bl1, Wl2, bl2, Wl3, bl3, (float*)d_out, n);
}